// Round 1
// baseline (328.294 us; speedup 1.0000x reference)
//
#include <hip/hip_runtime.h>

// StepConditionalLoReFT: out = h + Rn^T (W h + b - Rn h) per step s.
// All tensors FP32 (per reference). B=8 S=50 T=77 D=1024 r=16.
//
// Two kernels:
//  1) loreft_prep (50 blocks): Rn = R/max(||R||,eps), M = W - Rn -> bf16 in
//     workspace: Mg[s][r][d] (GEMM1 B-frag order), Rg[s][d][r] (GEMM2 A-frag
//     order). 3.3 MB total -> L2/L3 resident for the main kernel.
//  2) loreft_main (50 x 10 blocks, 4 independent waves, NO LDS, NO barriers):
//     GEMM1 c[tok,r] = bf16(H) M^T + b  (mfma 16x16x32 bf16, K=1024)
//     shuffle-transpose c -> B-frag; GEMM2-T delta^T = Rn^T c^T; epilogue
//     out = h + delta with nontemporal loads/stores (keep h L3-resident).

typedef __attribute__((ext_vector_type(8))) short short8;
typedef __attribute__((ext_vector_type(4))) float floatx4;

__device__ __forceinline__ short f2bf(float f) {
  unsigned u = __float_as_uint(f);
  u += 0x7fffu + ((u >> 16) & 1u);   // round-to-nearest-even
  return (short)(u >> 16);
}

#define S_ 50
#define T_ 77
#define NTOK 616   // B*T tokens per step s

// ================= prep kernel =================
__global__ __launch_bounds__(256) void loreft_prep(
    const float* __restrict__ RG, const float* __restrict__ WG,
    short* __restrict__ Mg, short* __restrict__ Rg) {
  __shared__ float RnL[16][1024];
  const int s = blockIdx.x;
  const int tid = threadIdx.x;
  const int lane = tid & 63;
  const int wvi = tid >> 6;

#pragma unroll
  for (int rr = 0; rr < 4; ++rr) {
    const int r = wvi * 4 + rr;
    const floatx4* Rrow = (const floatx4*)(RG + (size_t)((s * 16 + r) << 10));
    const floatx4* Wrow = (const floatx4*)(WG + (size_t)((s * 16 + r) << 10));
    floatx4 rv0 = Rrow[lane * 4 + 0];
    floatx4 rv1 = Rrow[lane * 4 + 1];
    floatx4 rv2 = Rrow[lane * 4 + 2];
    floatx4 rv3 = Rrow[lane * 4 + 3];
    float ss = 0.f;
#pragma unroll
    for (int j = 0; j < 4; ++j)
      ss += rv0[j] * rv0[j] + rv1[j] * rv1[j] + rv2[j] * rv2[j] + rv3[j] * rv3[j];
#pragma unroll
    for (int m = 1; m < 64; m <<= 1) ss += __shfl_xor(ss, m);
    const float inv = 1.0f / fmaxf(sqrtf(ss), 1e-12f);

    floatx4 wa0 = Wrow[lane * 4 + 0];
    floatx4 wa1 = Wrow[lane * 4 + 1];
    floatx4 wa2 = Wrow[lane * 4 + 2];
    floatx4 wa3 = Wrow[lane * 4 + 3];
    float rn[16];
    short8 m0, m1;
#pragma unroll
    for (int j = 0; j < 4; ++j) {
      rn[j]      = rv0[j] * inv;  m0[j]     = f2bf(wa0[j] - rn[j]);
      rn[4 + j]  = rv1[j] * inv;  m0[4 + j] = f2bf(wa1[j] - rn[4 + j]);
      rn[8 + j]  = rv2[j] * inv;  m1[j]     = f2bf(wa2[j] - rn[8 + j]);
      rn[12 + j] = rv3[j] * inv;  m1[4 + j] = f2bf(wa3[j] - rn[12 + j]);
    }
    // Mg[s][r][d] row-major bf16, lane covers d = lane*16 .. +15
    short* mdst = Mg + (size_t)(s * 16 + r) * 1024 + lane * 16;
    *(short8*)mdst = m0;
    *(short8*)(mdst + 8) = m1;
#pragma unroll
    for (int jj = 0; jj < 16; ++jj) RnL[r][lane * 16 + jj] = rn[jj];
  }
  __syncthreads();

  // Rg[s][d][r]: thread handles d = dd*256 + tid, writes 16 r-values (32 B)
#pragma unroll
  for (int dd = 0; dd < 4; ++dd) {
    const int d = dd * 256 + tid;
    short8 lo8, hi8;
#pragma unroll
    for (int rj = 0; rj < 8; ++rj) {
      lo8[rj] = f2bf(RnL[rj][d]);
      hi8[rj] = f2bf(RnL[rj + 8][d]);
    }
    short* dst = Rg + ((size_t)s * 1024 + d) * 16;
    *(short8*)dst = lo8;
    *(short8*)(dst + 8) = hi8;
  }
}

// ================= main kernel: no LDS, no barriers =================
__global__ __launch_bounds__(256, 2) void loreft_main(
    const float* __restrict__ hG, const float* __restrict__ bG,
    const short* __restrict__ Mg, const short* __restrict__ Rg,
    float* __restrict__ outG) {
  const int tid = threadIdx.x;
  const int lane = tid & 63;
  const int wvi = tid >> 6;       // wave 0..3, fully independent
  const int m16 = lane & 15;
  const int quad = lane >> 4;
  const int s = blockIdx.x;

  const int tokbase = blockIdx.y * 64 + wvi * 16;
  if (tokbase >= NTOK) return;    // wave-uniform: whole-wave early out
  int tokA = tokbase + m16; if (tokA > NTOK - 1) tokA = NTOK - 1;
  const int bb1 = tokA / T_;
  const int tt1 = tokA - bb1 * T_;
  const size_t rowoff = ((size_t)((bb1 * S_ + s) * T_ + tt1)) << 10;
  const float* hrow = hG + rowoff;
  const floatx4* hrow4 = (const floatx4*)hrow;
  // GEMM1 B-frag: lane (quad,m16) needs M[r=m16][k = kb*32 + quad*8 + j]
  const short* mrow = Mg + (size_t)(s * 16 + m16) * 1024 + quad * 8;

  floatx4 acc = {0.f, 0.f, 0.f, 0.f};
#pragma unroll 4
  for (int kb = 0; kb < 32; ++kb) {
    floatx4 p0 = hrow4[kb * 8 + quad * 2];        // temporal: re-read in epilogue
    floatx4 p1 = hrow4[kb * 8 + quad * 2 + 1];
    short8 af;
#pragma unroll
    for (int j = 0; j < 4; ++j) { af[j] = f2bf(p0[j]); af[4 + j] = f2bf(p1[j]); }
    short8 bf = *(const short8*)(mrow + kb * 32); // L2-resident fragments
    acc = __builtin_amdgcn_mfma_f32_16x16x32_bf16(af, bf, acc, 0, 0, 0);
  }

  // c: lane holds c[tok = quad*4 + i][r = m16]; add bias b[s][r]
  const float bias = bG[s * 16 + m16];
  float cf[4];
#pragma unroll
  for (int i = 0; i < 4; ++i) cf[i] = acc[i] + bias;

  // ========== transpose c -> B-frag of GEMM2-T via shuffles ==========
  // target lane L needs B[k=r=(L>>4)*8+j][n=tok=L&15] = c[tok][r];
  // source lane = (tok>>2)*16 + r, reg = tok&3.
  unsigned lo = ((unsigned)(unsigned short)f2bf(cf[0])) |
                (((unsigned)(unsigned short)f2bf(cf[1])) << 16);
  unsigned hi = ((unsigned)(unsigned short)f2bf(cf[2])) |
                (((unsigned)(unsigned short)f2bf(cf[3])) << 16);
  short8 bfrag;
  {
    const int srcbase = ((m16 >> 2) << 4) + ((quad & 1) << 3);
    const int regsel = m16 & 3;
#pragma unroll
    for (int j = 0; j < 8; ++j) {
      unsigned vlo = __shfl(lo, srcbase + j);
      unsigned vhi = __shfl(hi, srcbase + j);
      unsigned v32 = (regsel & 2) ? vhi : vlo;
      bfrag[j] = (short)((regsel & 1) ? (v32 >> 16) : (v32 & 0xffffu));
    }
  }
  const short8 zero8 = {0, 0, 0, 0, 0, 0, 0, 0};
  if (quad >= 2) bfrag = zero8;   // k = r in [16,32) is padding

  // ========== GEMM2-T + epilogue ==========
  // A-frag: lane needs Rn^T[d = dt*16 + m16][r = q16 .. q16+7] (quads 2/3 zero)
  // D: lane holds delta[d = dt*16 + quad*4 + i][tok = m16] -> float4 epilogue
  float* orow = outG + rowoff;
  const bool valE = (tokbase + m16) < NTOK;
  const int q16 = (quad & 1) << 3;
  const short* rbase = Rg + (size_t)s * (1024 * 16) + q16;

#pragma unroll 8
  for (int dt = 0; dt < 64; ++dt) {
    short8 ar = zero8;
    if (quad < 2) ar = *(const short8*)(rbase + (dt * 16 + m16) * 16);
    floatx4 z = {0.f, 0.f, 0.f, 0.f};
    floatx4 dv = __builtin_amdgcn_mfma_f32_16x16x32_bf16(ar, bfrag, z, 0, 0, 0);
    const int d0 = dt * 16 + quad * 4;
    if (valE) {
      // last use of h + streaming out: nontemporal keeps h L3-resident
      floatx4 hv = __builtin_nontemporal_load((const floatx4*)(hrow + d0));
      floatx4 o;
#pragma unroll
      for (int i = 0; i < 4; ++i) o[i] = hv[i] + dv[i];
      __builtin_nontemporal_store(o, (floatx4*)(orow + d0));
    }
  }
}

extern "C" void kernel_launch(void* const* d_in, const int* in_sizes, int n_in,
                              void* d_out, int out_size, void* d_ws, size_t ws_size,
                              hipStream_t stream) {
  const float* h = (const float*)d_in[0];
  const float* R = (const float*)d_in[1];
  const float* W = (const float*)d_in[2];
  const float* b = (const float*)d_in[3];
  // workspace: Mg (50*16*1024 bf16 = 1.64 MB) then Rg (same) = 3.28 MB total
  short* Mg = (short*)d_ws;
  short* Rg = Mg + (size_t)S_ * 16 * 1024;
  loreft_prep<<<dim3(S_), 256, 0, stream>>>(R, W, Mg, Rg);
  loreft_main<<<dim3(S_, 10), 256, 0, stream>>>(h, b, Mg, Rg, (float*)d_out);
}

// Round 2
// 282.372 us; speedup vs baseline: 1.1626x; 1.1626x over previous
//
#include <hip/hip_runtime.h>

// StepConditionalLoReFT: out = h + Rn^T (W h + b - Rn h) per step s.
// All tensors FP32 (per reference). B=8 S=50 T=77 D=1024 r=16.
//
// Two kernels:
//  1) loreft_prep (50 blocks): Rn = R/max(||R||,eps), M = W - Rn -> bf16 in
//     workspace: Mg[s][r][d] (GEMM1 B-frag order), Rg[s][d][r] (GEMM2 A-frag
//     order). 3.3 MB total -> L2-resident for the main kernel.
//  2) loreft_main (50 x 39 blocks, 128 thr = 2 waves, NO LDS, NO barriers):
//     each block owns one 16-token tile; both waves run GEMM1 (duplicate h
//     reads coalesce in L1/L2), then each wave computes half the d-range of
//     GEMM2 + epilogue. Explicit 4-deep register staging pipelines all
//     global loads (fixes round-1's VGPR=32 latency exposure).

typedef __attribute__((ext_vector_type(8))) short short8;
typedef __attribute__((ext_vector_type(4))) float floatx4;

__device__ __forceinline__ short f2bf(float f) {
  unsigned u = __float_as_uint(f);
  u += 0x7fffu + ((u >> 16) & 1u);   // round-to-nearest-even
  return (short)(u >> 16);
}

#define S_ 50
#define T_ 77
#define NTOK 616   // B*T tokens per step s

// ================= prep kernel =================
__global__ __launch_bounds__(256) void loreft_prep(
    const float* __restrict__ RG, const float* __restrict__ WG,
    short* __restrict__ Mg, short* __restrict__ Rg) {
  __shared__ float RnL[16][1024];
  const int s = blockIdx.x;
  const int tid = threadIdx.x;
  const int lane = tid & 63;
  const int wvi = tid >> 6;

#pragma unroll
  for (int rr = 0; rr < 4; ++rr) {
    const int r = wvi * 4 + rr;
    const floatx4* Rrow = (const floatx4*)(RG + (size_t)((s * 16 + r) << 10));
    const floatx4* Wrow = (const floatx4*)(WG + (size_t)((s * 16 + r) << 10));
    floatx4 rv0 = Rrow[lane * 4 + 0];
    floatx4 rv1 = Rrow[lane * 4 + 1];
    floatx4 rv2 = Rrow[lane * 4 + 2];
    floatx4 rv3 = Rrow[lane * 4 + 3];
    float ss = 0.f;
#pragma unroll
    for (int j = 0; j < 4; ++j)
      ss += rv0[j] * rv0[j] + rv1[j] * rv1[j] + rv2[j] * rv2[j] + rv3[j] * rv3[j];
#pragma unroll
    for (int m = 1; m < 64; m <<= 1) ss += __shfl_xor(ss, m);
    const float inv = 1.0f / fmaxf(sqrtf(ss), 1e-12f);

    floatx4 wa0 = Wrow[lane * 4 + 0];
    floatx4 wa1 = Wrow[lane * 4 + 1];
    floatx4 wa2 = Wrow[lane * 4 + 2];
    floatx4 wa3 = Wrow[lane * 4 + 3];
    float rn[16];
    short8 m0, m1;
#pragma unroll
    for (int j = 0; j < 4; ++j) {
      rn[j]      = rv0[j] * inv;  m0[j]     = f2bf(wa0[j] - rn[j]);
      rn[4 + j]  = rv1[j] * inv;  m0[4 + j] = f2bf(wa1[j] - rn[4 + j]);
      rn[8 + j]  = rv2[j] * inv;  m1[j]     = f2bf(wa2[j] - rn[8 + j]);
      rn[12 + j] = rv3[j] * inv;  m1[4 + j] = f2bf(wa3[j] - rn[12 + j]);
    }
    // Mg[s][r][d] row-major bf16, lane covers d = lane*16 .. +15
    short* mdst = Mg + (size_t)(s * 16 + r) * 1024 + lane * 16;
    *(short8*)mdst = m0;
    *(short8*)(mdst + 8) = m1;
#pragma unroll
    for (int jj = 0; jj < 16; ++jj) RnL[r][lane * 16 + jj] = rn[jj];
  }
  __syncthreads();

  // Rg[s][d][r]: thread handles d = dd*256 + tid, writes 16 r-values (32 B)
#pragma unroll
  for (int dd = 0; dd < 4; ++dd) {
    const int d = dd * 256 + tid;
    short8 lo8, hi8;
#pragma unroll
    for (int rj = 0; rj < 8; ++rj) {
      lo8[rj] = f2bf(RnL[rj][d]);
      hi8[rj] = f2bf(RnL[rj + 8][d]);
    }
    short* dst = Rg + ((size_t)s * 1024 + d) * 16;
    *(short8*)dst = lo8;
    *(short8*)(dst + 8) = hi8;
  }
}

// ================= main kernel: no LDS, no barriers, deep pipelining =======
__global__ __launch_bounds__(128, 4) void loreft_main(
    const float* __restrict__ hG, const float* __restrict__ bG,
    const short* __restrict__ Mg, const short* __restrict__ Rg,
    float* __restrict__ outG) {
  const int tid = threadIdx.x;
  const int lane = tid & 63;
  const int wvi = tid >> 6;       // wave 0..1, fully independent
  const int m16 = lane & 15;
  const int quad = lane >> 4;
  const int s = blockIdx.x;

  const int tokbase = blockIdx.y * 16;          // 39 tiles cover 616 tokens
  int tokA = tokbase + m16; if (tokA > NTOK - 1) tokA = NTOK - 1;
  const int bb1 = tokA / T_;
  const int tt1 = tokA - bb1 * T_;
  const size_t rowoff = ((size_t)((bb1 * S_ + s) * T_ + tt1)) << 10;
  const float* hrow = hG + rowoff;
  const floatx4* hrow4 = (const floatx4*)hrow;
  // GEMM1 B-frag: lane (quad,m16) needs M[r=m16][k = kb*32 + quad*8 + j]
  const short* mrow = Mg + (size_t)(s * 16 + m16) * 1024 + quad * 8;

  // ---------- GEMM1: c[tok, r] = H M^T, 4-deep staged pipeline ----------
  floatx4 acc = {0.f, 0.f, 0.f, 0.f};
  floatx4 ha[4], hb[4];
  short8 mf[4];
#pragma unroll
  for (int j = 0; j < 4; ++j) {                 // prologue: group 0 (kb 0..3)
    ha[j] = hrow4[j * 8 + quad * 2];
    hb[j] = hrow4[j * 8 + quad * 2 + 1];
    mf[j] = *(const short8*)(mrow + j * 32);
  }
#pragma unroll
  for (int g = 0; g < 8; ++g) {
    floatx4 na[4], nb[4];
    short8 nf[4];
    if (g < 7) {
#pragma unroll
      for (int j = 0; j < 4; ++j) {             // issue next group's loads
        const int kb = (g + 1) * 4 + j;
        na[j] = hrow4[kb * 8 + quad * 2];
        nb[j] = hrow4[kb * 8 + quad * 2 + 1];
        nf[j] = *(const short8*)(mrow + kb * 32);
      }
    }
#pragma unroll
    for (int j = 0; j < 4; ++j) {               // compute current group
      short8 af;
#pragma unroll
      for (int i = 0; i < 4; ++i) { af[i] = f2bf(ha[j][i]); af[4 + i] = f2bf(hb[j][i]); }
      acc = __builtin_amdgcn_mfma_f32_16x16x32_bf16(af, mf[j], acc, 0, 0, 0);
    }
    if (g < 7) {
#pragma unroll
      for (int j = 0; j < 4; ++j) { ha[j] = na[j]; hb[j] = nb[j]; mf[j] = nf[j]; }
    }
  }

  // c: lane holds c[tok = quad*4 + i][r = m16]; add bias b[s][r]
  const float bias = bG[s * 16 + m16];
  float cf[4];
#pragma unroll
  for (int i = 0; i < 4; ++i) cf[i] = acc[i] + bias;

  // ========== transpose c -> B-frag of GEMM2-T via shuffles ==========
  // target lane L needs B[k=r=(L>>4)*8+j][n=tok=L&15] = c[tok][r];
  // source lane = (tok>>2)*16 + r, reg = tok&3.
  unsigned lo = ((unsigned)(unsigned short)f2bf(cf[0])) |
                (((unsigned)(unsigned short)f2bf(cf[1])) << 16);
  unsigned hi = ((unsigned)(unsigned short)f2bf(cf[2])) |
                (((unsigned)(unsigned short)f2bf(cf[3])) << 16);
  short8 bfrag;
  {
    const int srcbase = ((m16 >> 2) << 4) + ((quad & 1) << 3);
    const int regsel = m16 & 3;
#pragma unroll
    for (int j = 0; j < 8; ++j) {
      unsigned vlo = __shfl(lo, srcbase + j);
      unsigned vhi = __shfl(hi, srcbase + j);
      unsigned v32 = (regsel & 2) ? vhi : vlo;
      bfrag[j] = (short)((regsel & 1) ? (v32 >> 16) : (v32 & 0xffffu));
    }
  }
  const short8 zero8 = {0, 0, 0, 0, 0, 0, 0, 0};
  if (quad >= 2) bfrag = zero8;   // k = r in [16,32) is padding

  // ========== GEMM2-T + epilogue: this wave owns dt = wvi*32 .. +31 ======
  // A-frag: lane needs Rn^T[d = dt*16 + m16][r = q16 .. q16+7] (quads 2/3 zero)
  // D: lane holds delta[d = dt*16 + quad*4 + i][tok = m16] -> float4 epilogue
  float* orow = outG + rowoff;
  const bool valE = (tokbase + m16) < NTOK;
  const int q16 = (quad & 1) << 3;
  const short* rbase = Rg + (size_t)s * (1024 * 16) + q16;
  const int dt0 = wvi * 32;

  short8 ar[4];
  floatx4 hv[4];
#pragma unroll
  for (int j = 0; j < 4; ++j) {                 // prologue: group 0
    const int dt = dt0 + j;
    ar[j] = (quad < 2) ? *(const short8*)(rbase + (dt * 16 + m16) * 16) : zero8;
    hv[j] = *(const floatx4*)(hrow + dt * 16 + quad * 4);
  }
#pragma unroll
  for (int g = 0; g < 8; ++g) {
    short8 nr[4];
    floatx4 nh[4];
    if (g < 7) {
#pragma unroll
      for (int j = 0; j < 4; ++j) {             // issue next group's loads
        const int dt = dt0 + (g + 1) * 4 + j;
        nr[j] = (quad < 2) ? *(const short8*)(rbase + (dt * 16 + m16) * 16) : zero8;
        nh[j] = *(const floatx4*)(hrow + dt * 16 + quad * 4);
      }
    }
#pragma unroll
    for (int j = 0; j < 4; ++j) {               // compute + store current
      const int dt = dt0 + g * 4 + j;
      floatx4 z = {0.f, 0.f, 0.f, 0.f};
      floatx4 dv = __builtin_amdgcn_mfma_f32_16x16x32_bf16(ar[j], bfrag, z, 0, 0, 0);
      if (valE) {
        floatx4 o;
#pragma unroll
        for (int i = 0; i < 4; ++i) o[i] = hv[j][i] + dv[i];
        *(floatx4*)(orow + dt * 16 + quad * 4) = o;
      }
    }
    if (g < 7) {
#pragma unroll
      for (int j = 0; j < 4; ++j) { ar[j] = nr[j]; hv[j] = nh[j]; }
    }
  }
}

extern "C" void kernel_launch(void* const* d_in, const int* in_sizes, int n_in,
                              void* d_out, int out_size, void* d_ws, size_t ws_size,
                              hipStream_t stream) {
  const float* h = (const float*)d_in[0];
  const float* R = (const float*)d_in[1];
  const float* W = (const float*)d_in[2];
  const float* b = (const float*)d_in[3];
  // workspace: Mg (50*16*1024 bf16 = 1.64 MB) then Rg (same) = 3.28 MB total
  short* Mg = (short*)d_ws;
  short* Rg = Mg + (size_t)S_ * 16 * 1024;
  loreft_prep<<<dim3(S_), 256, 0, stream>>>(R, W, Mg, Rg);
  loreft_main<<<dim3(S_, 39), 128, 0, stream>>>(h, b, Mg, Rg, (float*)d_out);
}